// Round 5
// baseline (395.137 us; speedup 1.0000x reference)
//
#include <hip/hip_runtime.h>
#include <cstdint>

#define NFEAT 4096
#define NHALF 2048
#define DDIM  512
#define QROWS 32768

typedef unsigned short u16;
typedef unsigned int   u32;
typedef unsigned long long u64;

typedef __bf16 bf16x8_t __attribute__((ext_vector_type(8)));
typedef float  f32x4_t  __attribute__((ext_vector_type(4)));
typedef u32    u32x4_t  __attribute__((ext_vector_type(4)));

typedef const __attribute__((address_space(1))) void* gas_ptr;
typedef __attribute__((address_space(3))) void* las_ptr;

__device__ __forceinline__ u16 f2bf(float f) {
  u32 u = __float_as_uint(f);
  u32 r = u + 0x7FFFu + ((u >> 16) & 1u);
  return (u16)(r >> 16);
}

// monotonic unsigned encoding of float (no NaN/Inf expected)
__device__ __forceinline__ u32 fkey(float f) {
  u32 u = __float_as_uint(f);
  return (u & 0x80000000u) ? ~u : (u | 0x80000000u);
}

// ---------------- kernel 1: l2-normalize rows -> bf16 ----------------
__global__ void k_norm(const float* __restrict__ zi, const float* __restrict__ zj,
                       const float* __restrict__ queue,
                       u16* __restrict__ featb, u16* __restrict__ queueb) {
  int gw = (int)((blockIdx.x * blockDim.x + threadIdx.x) >> 6);
  int lane = threadIdx.x & 63;
  const float* src; u16* dst;
  if (gw < NFEAT) {
    src = (gw < NHALF) ? (zi + (size_t)gw * DDIM) : (zj + (size_t)(gw - NHALF) * DDIM);
    dst = featb + (size_t)gw * DDIM;
  } else {
    int r = gw - NFEAT;
    src = queue + (size_t)r * DDIM;
    dst = queueb + (size_t)r * DDIM;
  }
  float4 v0 = reinterpret_cast<const float4*>(src)[lane * 2];
  float4 v1 = reinterpret_cast<const float4*>(src)[lane * 2 + 1];
  float ss = v0.x*v0.x + v0.y*v0.y + v0.z*v0.z + v0.w*v0.w
           + v1.x*v1.x + v1.y*v1.y + v1.z*v1.z + v1.w*v1.w;
  #pragma unroll
  for (int off = 32; off >= 1; off >>= 1) ss += __shfl_xor(ss, off);
  float inv = 1.0f / fmaxf(sqrtf(ss), 1e-12f);
  ushort4 o0, o1;
  o0.x = f2bf(v0.x * inv); o0.y = f2bf(v0.y * inv);
  o0.z = f2bf(v0.z * inv); o0.w = f2bf(v0.w * inv);
  o1.x = f2bf(v1.x * inv); o1.y = f2bf(v1.y * inv);
  o1.z = f2bf(v1.z * inv); o1.w = f2bf(v1.w * inv);
  reinterpret_cast<ushort4*>(dst)[lane * 2]     = o0;
  reinterpret_cast<ushort4*>(dst)[lane * 2 + 1] = o1;
}

// ---------------- 8-phase 256x256 GEMM (m201-style, derived waits) ----------------
// BM=BN=256, BK=64, 512 thr = 8 waves (2M x 4N), wave tile 128x64 (8m x 4n frags).
// LDS: 2 bufs x (A 32KB + B 32KB) = 128 KB. Half h = rows h*128..h*128+127.
// Swizzle: LDS (row, slot u) holds global k-slot u ^ (row&7) (slot = 16B = 8 bf16).
// Staged linearly by glds (thread tid covers row tid>>3 of a 64-row line, slot tid&7,
// source k pre-permuted). asm ds_read_b128 + manual lgkmcnt/sched_barrier (rule 18).
// Iter j computes tiles 2j (buf0, phases 1-4 = quadrants q00,q01,q10,q11) and
// 2j+1 (buf1, phases 5-8). Stages: p1/p2: A(2j+1)->buf1, p3/p4: B(2j+2)->buf0,
// p5/p6: A(2j+2)->buf0, p7/p8: B(2j+3)->buf1. vmcnt(4) at p4 & p8 (p4 of last
// iter: vmcnt(0)). Each vmcnt(4) leaves exactly the 2 newest half-tiles in
// flight => next tile fully landed; each stage target is >=1 barrier dead.

#define WAIT_LGKM0() do { asm volatile("s_waitcnt lgkmcnt(0)" ::: "memory"); \
                          __builtin_amdgcn_sched_barrier(0); } while (0)
#define VMCNT4() asm volatile("s_waitcnt vmcnt(4)" ::: "memory")
#define VMCNT0() asm volatile("s_waitcnt vmcnt(0)" ::: "memory")
#define SBAR() __builtin_amdgcn_s_barrier()

// ---------------- kernel 2: features @ queue^T with fused row-argmax ----------------
__global__ __launch_bounds__(512, 2) void k_argmax_gemm(
    const u16* __restrict__ featb, const u16* __restrict__ queueb,
    u64* __restrict__ part) {
  __shared__ u16 lds[65536];
  const int tid = threadIdx.x;
  const int w = tid >> 6, lane = tid & 63;
  const int wr = w >> 2, wc = w & 3;
  const int li = lane & 15, lg = lane >> 4;
  const int bid = (int)blockIdx.x;
  const int wg = (bid & 7) * 256 + (bid >> 3);   // bijective XCD swizzle (2048 = 8x256)
  const int mt = wg & 15, qt = wg >> 4;
  const int brow = mt * 256, bcol = qt * 256;

  // staging: thread covers (row = h*128 + l*64 + srw, slot = tid&7), src k-slot pre-permuted
  const int srw = tid >> 3;
  const int ssl = (tid & 7) ^ ((tid >> 3) & 7);
  const u16* gA = featb  + (size_t)brow * DDIM + ssl * 8;
  const u16* gB = queueb + (size_t)bcol * DDIM + ssl * 8;
  const int ldsw = w * 512;

  // read-side swizzled slot offsets (elems) for k-half 0/1
  const int sx = li & 7;
  const int u0 = (lg ^ sx) * 8;
  const int u1 = ((4 + lg) ^ sx) * 8;
  const int aBase = wr * 8192 + li * 64;                                    // + m*1024
  const int bBase = 16384 + (wc >> 1) * 8192 + ((wc & 1) * 64 + li) * 64;   // + n*1024

  f32x4_t acc[8][4] = {};

  auto stA = [&](int b, int t, int h) {
    #pragma unroll
    for (int l = 0; l < 2; l++) {
      const u16* src = gA + (size_t)(h * 128 + l * 64 + srw) * DDIM + t * 64;
      __builtin_amdgcn_global_load_lds((gas_ptr)src,
          (las_ptr)&lds[b * 32768 + h * 8192 + l * 4096 + ldsw], 16, 0, 0);
    }
  };
  auto stB = [&](int b, int t, int h) {
    #pragma unroll
    for (int l = 0; l < 2; l++) {
      const u16* src = gB + (size_t)(h * 128 + l * 64 + srw) * DDIM + t * 64;
      __builtin_amdgcn_global_load_lds((gas_ptr)src,
          (las_ptr)&lds[b * 32768 + 16384 + h * 8192 + l * 4096 + ldsw], 16, 0, 0);
    }
  };
  auto rd = [&](int elem) -> bf16x8_t {
    u32x4_t r;
    u32 addr = (u32)(size_t)(las_ptr)&lds[elem];
    asm volatile("ds_read_b128 %0, %1" : "=v"(r) : "v"(addr));
    return __builtin_bit_cast(bf16x8_t, r);
  };

  bf16x8_t A03[8], A47[8], Bq[4], Bq2[4];

  // prologue: B(0), A(0), B(1); wait until tile 0 landed (keep newest 4 = B(1))
  stB(0, 0, 0); stB(0, 0, 1); stA(0, 0, 0); stA(0, 0, 1); stB(1, 1, 0); stB(1, 1, 1);
  VMCNT4();
  SBAR();

  #pragma unroll
  for (int j = 0; j < 4; j++) {
    #pragma unroll
    for (int half = 0; half < 2; half++) {          // half 0: buf0/tile 2j; half 1: buf1/tile 2j+1
      const int b = half;
      const int bb = b * 32768;
      // ---- phase A (q00): read A03 + Bq ----
      #pragma unroll
      for (int m = 0; m < 4; m++) {
        A03[m * 2]     = rd(bb + aBase + m * 1024 + u0);
        A03[m * 2 + 1] = rd(bb + aBase + m * 1024 + u1);
      }
      #pragma unroll
      for (int n = 0; n < 2; n++) {
        Bq[n * 2]      = rd(bb + bBase + n * 1024 + u0);
        Bq[n * 2 + 1]  = rd(bb + bBase + n * 1024 + u1);
      }
      if (half == 0) stA(1, 2 * j + 1, 0); else if (j < 3) stA(0, 2 * j + 2, 0);
      SBAR();
      WAIT_LGKM0();
      __builtin_amdgcn_s_setprio(1);
      #pragma unroll
      for (int kk = 0; kk < 2; kk++)
        #pragma unroll
        for (int m = 0; m < 4; m++)
          #pragma unroll
          for (int n = 0; n < 2; n++)
            acc[m][n] = __builtin_amdgcn_mfma_f32_16x16x32_bf16(A03[m*2+kk], Bq[n*2+kk], acc[m][n], 0, 0, 0);
      __builtin_amdgcn_s_setprio(0);
      SBAR();
      // ---- phase B (q01): read Bq2 ----
      #pragma unroll
      for (int n = 0; n < 2; n++) {
        Bq2[n * 2]     = rd(bb + bBase + (n + 2) * 1024 + u0);
        Bq2[n * 2 + 1] = rd(bb + bBase + (n + 2) * 1024 + u1);
      }
      if (half == 0) stA(1, 2 * j + 1, 1); else if (j < 3) stA(0, 2 * j + 2, 1);
      SBAR();
      WAIT_LGKM0();
      __builtin_amdgcn_s_setprio(1);
      #pragma unroll
      for (int kk = 0; kk < 2; kk++)
        #pragma unroll
        for (int m = 0; m < 4; m++)
          #pragma unroll
          for (int n = 0; n < 2; n++)
            acc[m][2 + n] = __builtin_amdgcn_mfma_f32_16x16x32_bf16(A03[m*2+kk], Bq2[n*2+kk], acc[m][2+n], 0, 0, 0);
      __builtin_amdgcn_s_setprio(0);
      SBAR();
      // ---- phase C (q10): read A47 ----
      #pragma unroll
      for (int m = 0; m < 4; m++) {
        A47[m * 2]     = rd(bb + aBase + (m + 4) * 1024 + u0);
        A47[m * 2 + 1] = rd(bb + aBase + (m + 4) * 1024 + u1);
      }
      if (j < 3) { if (half == 0) stB(0, 2 * j + 2, 0); else stB(1, 2 * j + 3, 0); }
      SBAR();
      WAIT_LGKM0();
      __builtin_amdgcn_s_setprio(1);
      #pragma unroll
      for (int kk = 0; kk < 2; kk++)
        #pragma unroll
        for (int m = 0; m < 4; m++)
          #pragma unroll
          for (int n = 0; n < 2; n++)
            acc[4 + m][n] = __builtin_amdgcn_mfma_f32_16x16x32_bf16(A47[m*2+kk], Bq[n*2+kk], acc[4+m][n], 0, 0, 0);
      __builtin_amdgcn_s_setprio(0);
      SBAR();
      // ---- phase D (q11): no reads; K-tile boundary vmcnt ----
      if (j < 3) { if (half == 0) stB(0, 2 * j + 2, 1); else stB(1, 2 * j + 3, 1); }
      if (half == 0) { if (j < 3) VMCNT4(); else VMCNT0(); }
      else           { if (j < 3) VMCNT4(); }
      SBAR();
      __builtin_amdgcn_s_setprio(1);
      #pragma unroll
      for (int kk = 0; kk < 2; kk++)
        #pragma unroll
        for (int m = 0; m < 4; m++)
          #pragma unroll
          for (int n = 0; n < 2; n++)
            acc[4 + m][2 + n] = __builtin_amdgcn_mfma_f32_16x16x32_bf16(A47[m*2+kk], Bq2[n*2+kk], acc[4+m][2+n], 0, 0, 0);
      __builtin_amdgcn_s_setprio(0);
      SBAR();
    }
  }

  // epilogue: per-row argmax over this block's 256 cols (wave owns 64 cols)
  #pragma unroll
  for (int m = 0; m < 8; m++) {
    #pragma unroll
    for (int j = 0; j < 4; j++) {
      u64 best = 0;
      #pragma unroll
      for (int n = 0; n < 4; n++) {
        float v = acc[m][n][j];
        u32 col = (u32)(bcol + wc * 64 + n * 16 + li);
        u64 key = ((u64)fkey(v) << 32) | (u64)(0xFFFFFFFFu - col);
        best = best > key ? best : key;
      }
      #pragma unroll
      for (int off = 1; off < 16; off <<= 1) {
        u64 o = __shfl_xor(best, off);
        best = best > o ? best : o;
      }
      if (li == 0) {
        int row = brow + wr * 128 + m * 16 + lg * 4 + j;
        part[(size_t)row * 512 + (qt * 4 + wc)] = best;
      }
    }
  }
}

// ---------------- kernel 3: reduce argmax partials -> nn_idx ----------------
__global__ void k_argmax_reduce(const u64* __restrict__ part, int* __restrict__ nnidx) {
  int row = (int)((blockIdx.x * blockDim.x + threadIdx.x) >> 6);
  int lane = threadIdx.x & 63;
  const u64* p = part + (size_t)row * 512;
  u64 best = 0;
  #pragma unroll
  for (int i = 0; i < 8; i++) { u64 v = p[lane * 8 + i]; best = best > v ? best : v; }
  #pragma unroll
  for (int off = 1; off < 64; off <<= 1) { u64 o = __shfl_xor(best, off); best = best > o ? best : o; }
  if (lane == 0) nnidx[row] = (int)(0xFFFFFFFFu - (u32)(best & 0xFFFFFFFFu));
}

// ---------------- kernel 4: sim = nn_feats @ features^T / T, fused lse + positives ----
__global__ __launch_bounds__(512, 2) void k_sim_gemm(
    const u16* __restrict__ featb, const u16* __restrict__ queueb,
    const int* __restrict__ nnidx,
    float2* __restrict__ lsep, float* __restrict__ pos) {
  __shared__ u16 lds[65536];
  const int tid = threadIdx.x;
  const int w = tid >> 6, lane = tid & 63;
  const int wr = w >> 2, wc = w & 3;
  const int li = lane & 15, lg = lane >> 4;
  const int bid = (int)blockIdx.x;
  const int wg = (bid & 7) * 32 + (bid >> 3);     // XCD swizzle (256 = 8x32)
  const int mt = wg & 15, ct = wg >> 4;
  const int brow = mt * 256, bcol = ct * 256;

  const int srw = tid >> 3;
  const int ssl = (tid & 7) ^ ((tid >> 3) & 7);
  int rIdx[4];
  #pragma unroll
  for (int h = 0; h < 2; h++)
    #pragma unroll
    for (int l = 0; l < 2; l++)
      rIdx[h * 2 + l] = nnidx[brow + h * 128 + l * 64 + srw];
  const u16* gB = featb + (size_t)bcol * DDIM + ssl * 8;
  const int ldsw = w * 512;

  const int sx = li & 7;
  const int u0 = (lg ^ sx) * 8;
  const int u1 = ((4 + lg) ^ sx) * 8;
  const int aBase = wr * 8192 + li * 64;
  const int bBase = 16384 + (wc >> 1) * 8192 + ((wc & 1) * 64 + li) * 64;

  f32x4_t acc[8][4] = {};

  auto stA = [&](int b, int t, int h) {
    #pragma unroll
    for (int l = 0; l < 2; l++) {
      const u16* src = queueb + (size_t)rIdx[h * 2 + l] * DDIM + t * 64 + ssl * 8;
      __builtin_amdgcn_global_load_lds((gas_ptr)src,
          (las_ptr)&lds[b * 32768 + h * 8192 + l * 4096 + ldsw], 16, 0, 0);
    }
  };
  auto stB = [&](int b, int t, int h) {
    #pragma unroll
    for (int l = 0; l < 2; l++) {
      const u16* src = gB + (size_t)(h * 128 + l * 64 + srw) * DDIM + t * 64;
      __builtin_amdgcn_global_load_lds((gas_ptr)src,
          (las_ptr)&lds[b * 32768 + 16384 + h * 8192 + l * 4096 + ldsw], 16, 0, 0);
    }
  };
  auto rd = [&](int elem) -> bf16x8_t {
    u32x4_t r;
    u32 addr = (u32)(size_t)(las_ptr)&lds[elem];
    asm volatile("ds_read_b128 %0, %1" : "=v"(r) : "v"(addr));
    return __builtin_bit_cast(bf16x8_t, r);
  };

  bf16x8_t A03[8], A47[8], Bq[4], Bq2[4];

  stB(0, 0, 0); stB(0, 0, 1); stA(0, 0, 0); stA(0, 0, 1); stB(1, 1, 0); stB(1, 1, 1);
  VMCNT4();
  SBAR();

  #pragma unroll
  for (int j = 0; j < 4; j++) {
    #pragma unroll
    for (int half = 0; half < 2; half++) {
      const int b = half;
      const int bb = b * 32768;
      #pragma unroll
      for (int m = 0; m < 4; m++) {
        A03[m * 2]     = rd(bb + aBase + m * 1024 + u0);
        A03[m * 2 + 1] = rd(bb + aBase + m * 1024 + u1);
      }
      #pragma unroll
      for (int n = 0; n < 2; n++) {
        Bq[n * 2]      = rd(bb + bBase + n * 1024 + u0);
        Bq[n * 2 + 1]  = rd(bb + bBase + n * 1024 + u1);
      }
      if (half == 0) stA(1, 2 * j + 1, 0); else if (j < 3) stA(0, 2 * j + 2, 0);
      SBAR();
      WAIT_LGKM0();
      __builtin_amdgcn_s_setprio(1);
      #pragma unroll
      for (int kk = 0; kk < 2; kk++)
        #pragma unroll
        for (int m = 0; m < 4; m++)
          #pragma unroll
          for (int n = 0; n < 2; n++)
            acc[m][n] = __builtin_amdgcn_mfma_f32_16x16x32_bf16(A03[m*2+kk], Bq[n*2+kk], acc[m][n], 0, 0, 0);
      __builtin_amdgcn_s_setprio(0);
      SBAR();
      #pragma unroll
      for (int n = 0; n < 2; n++) {
        Bq2[n * 2]     = rd(bb + bBase + (n + 2) * 1024 + u0);
        Bq2[n * 2 + 1] = rd(bb + bBase + (n + 2) * 1024 + u1);
      }
      if (half == 0) stA(1, 2 * j + 1, 1); else if (j < 3) stA(0, 2 * j + 2, 1);
      SBAR();
      WAIT_LGKM0();
      __builtin_amdgcn_s_setprio(1);
      #pragma unroll
      for (int kk = 0; kk < 2; kk++)
        #pragma unroll
        for (int m = 0; m < 4; m++)
          #pragma unroll
          for (int n = 0; n < 2; n++)
            acc[m][2 + n] = __builtin_amdgcn_mfma_f32_16x16x32_bf16(A03[m*2+kk], Bq2[n*2+kk], acc[m][2+n], 0, 0, 0);
      __builtin_amdgcn_s_setprio(0);
      SBAR();
      #pragma unroll
      for (int m = 0; m < 4; m++) {
        A47[m * 2]     = rd(bb + aBase + (m + 4) * 1024 + u0);
        A47[m * 2 + 1] = rd(bb + aBase + (m + 4) * 1024 + u1);
      }
      if (j < 3) { if (half == 0) stB(0, 2 * j + 2, 0); else stB(1, 2 * j + 3, 0); }
      SBAR();
      WAIT_LGKM0();
      __builtin_amdgcn_s_setprio(1);
      #pragma unroll
      for (int kk = 0; kk < 2; kk++)
        #pragma unroll
        for (int m = 0; m < 4; m++)
          #pragma unroll
          for (int n = 0; n < 2; n++)
            acc[4 + m][n] = __builtin_amdgcn_mfma_f32_16x16x32_bf16(A47[m*2+kk], Bq[n*2+kk], acc[4+m][n], 0, 0, 0);
      __builtin_amdgcn_s_setprio(0);
      SBAR();
      if (j < 3) { if (half == 0) stB(0, 2 * j + 2, 1); else stB(1, 2 * j + 3, 1); }
      if (half == 0) { if (j < 3) VMCNT4(); else VMCNT0(); }
      else           { if (j < 3) VMCNT4(); }
      SBAR();
      __builtin_amdgcn_s_setprio(1);
      #pragma unroll
      for (int kk = 0; kk < 2; kk++)
        #pragma unroll
        for (int m = 0; m < 4; m++)
          #pragma unroll
          for (int n = 0; n < 2; n++)
            acc[4 + m][2 + n] = __builtin_amdgcn_mfma_f32_16x16x32_bf16(A47[m*2+kk], Bq2[n*2+kk], acc[4+m][2+n], 0, 0, 0);
      __builtin_amdgcn_s_setprio(0);
      SBAR();
    }
  }

  // epilogue: scale by 1/T=2, positives, diag mask, per-row (max, sumexp) over 64 cols
  #pragma unroll
  for (int m = 0; m < 8; m++) {
    #pragma unroll
    for (int j = 0; j < 4; j++) {
      int row = brow + wr * 128 + m * 16 + lg * 4 + j;
      float vals[4];
      float vmax = -3.0e38f;
      #pragma unroll
      for (int n = 0; n < 4; n++) {
        int col = bcol + wc * 64 + n * 16 + li;
        float v = acc[m][n][j] * 2.0f;
        if (col == (row ^ NHALF)) pos[row] = v;   // positive sample (unique writer)
        if (col == row) v = -1.0e30f;             // diag mask
        vals[n] = v;
        vmax = fmaxf(vmax, v);
      }
      float sum = 0.f;
      #pragma unroll
      for (int n = 0; n < 4; n++) sum += __expf(vals[n] - vmax);
      #pragma unroll
      for (int off = 1; off < 16; off <<= 1) {
        float mo = __shfl_xor(vmax, off);
        float so = __shfl_xor(sum, off);
        float M = fmaxf(vmax, mo);
        sum = sum * __expf(vmax - M) + so * __expf(mo - M);
        vmax = M;
      }
      if (li == 0) lsep[(size_t)row * 64 + (ct * 4 + wc)] = make_float2(vmax, sum);
    }
  }
}

// ---------------- kernel 5: per-row logsumexp merge ----------------
__global__ void k_lse(const float2* __restrict__ lsep, float* __restrict__ lse) {
  int row = (int)((blockIdx.x * blockDim.x + threadIdx.x) >> 6);
  int lane = threadIdx.x & 63;
  float2 p = lsep[(size_t)row * 64 + lane];
  float m = p.x, s = p.y;
  #pragma unroll
  for (int off = 1; off < 64; off <<= 1) {
    float mo = __shfl_xor(m, off), so = __shfl_xor(s, off);
    float M = fmaxf(m, mo);
    s = s * __expf(m - M) + so * __expf(mo - M);
    m = M;
  }
  if (lane == 0) lse[row] = m + __logf(s);
}

// ---------------- kernel 6: final scalar ----------------
__global__ void k_final(const float* __restrict__ lse, const float* __restrict__ pos,
                        float* __restrict__ out) {
  __shared__ float red[4];
  int tid = threadIdx.x;
  float a = 0.f;
  for (int i = tid; i < NFEAT; i += 256) a += lse[i] - pos[i];
  #pragma unroll
  for (int off = 32; off >= 1; off >>= 1) a += __shfl_xor(a, off);
  if ((tid & 63) == 0) red[tid >> 6] = a;
  __syncthreads();
  if (tid == 0) out[0] = (red[0] + red[1] + red[2] + red[3]) / (float)NFEAT;
}

extern "C" void kernel_launch(void* const* d_in, const int* in_sizes, int n_in,
                              void* d_out, int out_size, void* d_ws, size_t ws_size,
                              hipStream_t stream) {
  const float* zi    = (const float*)d_in[0];
  const float* zj    = (const float*)d_in[1];
  const float* queue = (const float*)d_in[2];
  float* out = (float*)d_out;
  char* ws = (char*)d_ws;

  // ws layout (bytes):
  u16*    queueb = (u16*)(ws + 0);               // 32768*512*2 = 33554432
  u16*    featb  = (u16*)(ws + 33554432);        // 4096*512*2  = 4194304
  u64*    part   = (u64*)(ws + 37748736);        // 4096*512*8  = 16777216
  int*    nnidx  = (int*)(ws + 54525952);        // 4096*4      = 16384
  float2* lsep   = (float2*)(ws + 54542336);     // 4096*64*8   = 2097152
  float*  pos    = (float*)(ws + 56639488);      // 4096*4      = 16384
  float*  lse    = (float*)(ws + 56655872);      // 4096*4      = 16384
  // total = 56672256 bytes (~54 MB)

  k_norm<<<9216, 256, 0, stream>>>(zi, zj, queue, featb, queueb);
  k_argmax_gemm<<<2048, 512, 0, stream>>>(featb, queueb, part);
  k_argmax_reduce<<<1024, 256, 0, stream>>>(part, nnidx);
  k_sim_gemm<<<256, 512, 0, stream>>>(featb, queueb, nnidx, lsep, pos);
  k_lse<<<1024, 256, 0, stream>>>(lsep, lse);
  k_final<<<1, 256, 0, stream>>>(lse, pos, out);
}

// Round 6
// 247.260 us; speedup vs baseline: 1.5981x; 1.5981x over previous
//
#include <hip/hip_runtime.h>
#include <cstdint>

#define NFEAT 4096
#define NHALF 2048
#define DDIM  512
#define QROWS 32768

typedef unsigned short u16;
typedef unsigned int   u32;
typedef unsigned long long u64;

typedef __bf16 bf16x8_t __attribute__((ext_vector_type(8)));
typedef float  f32x4_t  __attribute__((ext_vector_type(4)));
typedef u32    u32x4_t  __attribute__((ext_vector_type(4)));

typedef const __attribute__((address_space(1))) void* gas_ptr;
typedef __attribute__((address_space(3))) void* las_ptr;

__device__ __forceinline__ u16 f2bf(float f) {
  u32 u = __float_as_uint(f);
  u32 r = u + 0x7FFFu + ((u >> 16) & 1u);
  return (u16)(r >> 16);
}

// monotonic unsigned encoding of float (no NaN/Inf expected)
__device__ __forceinline__ u32 fkey(float f) {
  u32 u = __float_as_uint(f);
  return (u & 0x80000000u) ? ~u : (u | 0x80000000u);
}

// ---------------- kernel 1: l2-normalize rows -> bf16 ----------------
__global__ void k_norm(const float* __restrict__ zi, const float* __restrict__ zj,
                       const float* __restrict__ queue,
                       u16* __restrict__ featb, u16* __restrict__ queueb) {
  int gw = (int)((blockIdx.x * blockDim.x + threadIdx.x) >> 6);
  int lane = threadIdx.x & 63;
  const float* src; u16* dst;
  if (gw < NFEAT) {
    src = (gw < NHALF) ? (zi + (size_t)gw * DDIM) : (zj + (size_t)(gw - NHALF) * DDIM);
    dst = featb + (size_t)gw * DDIM;
  } else {
    int r = gw - NFEAT;
    src = queue + (size_t)r * DDIM;
    dst = queueb + (size_t)r * DDIM;
  }
  float4 v0 = reinterpret_cast<const float4*>(src)[lane * 2];
  float4 v1 = reinterpret_cast<const float4*>(src)[lane * 2 + 1];
  float ss = v0.x*v0.x + v0.y*v0.y + v0.z*v0.z + v0.w*v0.w
           + v1.x*v1.x + v1.y*v1.y + v1.z*v1.z + v1.w*v1.w;
  #pragma unroll
  for (int off = 32; off >= 1; off >>= 1) ss += __shfl_xor(ss, off);
  float inv = 1.0f / fmaxf(sqrtf(ss), 1e-12f);
  ushort4 o0, o1;
  o0.x = f2bf(v0.x * inv); o0.y = f2bf(v0.y * inv);
  o0.z = f2bf(v0.z * inv); o0.w = f2bf(v0.w * inv);
  o1.x = f2bf(v1.x * inv); o1.y = f2bf(v1.y * inv);
  o1.z = f2bf(v1.z * inv); o1.w = f2bf(v1.w * inv);
  reinterpret_cast<ushort4*>(dst)[lane * 2]     = o0;
  reinterpret_cast<ushort4*>(dst)[lane * 2 + 1] = o1;
}

// ---------------- 8-phase 256x256 GEMM (m201-style, derived waits) ----------------
// Same phase/stage/vmcnt ledger as R5 (verified correct). R6 change: slim
// addressing to kill the R5 scratch spill -- ds_reads use 4 standing byte
// addresses + literal offset: immediates; staging uses precomputed row
// pointers + unroll-folded t*128B offsets. Frag live peak = 64 VGPRs
// (A03 dies before A47 is born; B reads done by p2 so p3/p4 may stage B).

#define WAIT_LGKM0() do { asm volatile("s_waitcnt lgkmcnt(0)" ::: "memory"); \
                          __builtin_amdgcn_sched_barrier(0); } while (0)
#define VMCNT4() asm volatile("s_waitcnt vmcnt(4)" ::: "memory")
#define VMCNT0() asm volatile("s_waitcnt vmcnt(0)" ::: "memory")
#define SBAR() __builtin_amdgcn_s_barrier()
#define RD(dst, base, off) asm volatile("ds_read_b128 %0, %1 offset:" off \
                                        : "=v"(dst) : "v"(base))
#define MFMA_Q(MB, NB, AF, BF) do { \
  __builtin_amdgcn_s_setprio(1); \
  _Pragma("unroll") \
  for (int kk_ = 0; kk_ < 2; kk_++) \
    _Pragma("unroll") \
    for (int m_ = 0; m_ < 4; m_++) \
      _Pragma("unroll") \
      for (int n_ = 0; n_ < 2; n_++) \
        acc[MB + m_][NB + n_] = __builtin_amdgcn_mfma_f32_16x16x32_bf16( \
            AF[m_*2+kk_], BF[n_*2+kk_], acc[MB+m_][NB+n_], 0, 0, 0); \
  __builtin_amdgcn_s_setprio(0); } while (0)

// ---------------- kernel 2: features @ queue^T with fused row-argmax ----------------
__global__ __launch_bounds__(512, 2) void k_argmax_gemm(
    const u16* __restrict__ featb, const u16* __restrict__ queueb,
    u64* __restrict__ part) {
  __shared__ u16 lds[65536];
  const int tid = threadIdx.x;
  const int w = tid >> 6, lane = tid & 63;
  const int wr = w >> 2, wc = w & 3;
  const int li = lane & 15, lg = lane >> 4;
  const int bid = (int)blockIdx.x;
  const int wg = (bid & 7) * 256 + (bid >> 3);   // bijective XCD swizzle (2048 = 8x256)
  const int mt = wg & 15, qt = wg >> 4;
  const int brow = mt * 256, bcol = qt * 256;

  // staging geometry: thread covers (row = h*128 + l*64 + srw, 16B slot tid&7),
  // source k-slot pre-permuted to realize the XOR swizzle with linear LDS dest
  const int srw = tid >> 3;
  const int ssl = (tid & 7) ^ ((tid >> 3) & 7);
  const int ldsw = w * 512;
  const u16* pA[4]; const u16* pB[4];
  #pragma unroll
  for (int h = 0; h < 2; h++)
    #pragma unroll
    for (int l = 0; l < 2; l++) {
      pA[h*2+l] = featb  + (size_t)(brow + h*128 + l*64 + srw) * DDIM + ssl * 8;
      pB[h*2+l] = queueb + (size_t)(bcol + h*128 + l*64 + srw) * DDIM + ssl * 8;
    }

  // read-side: 4 standing byte addresses (A/B x k-half), literal offsets for m/n
  const int sx = li & 7;
  const int u0 = (lg ^ sx) * 8;
  const int u1 = ((4 + lg) ^ sx) * 8;
  const int aBase = wr * 8192 + li * 64;
  const int bBase = 16384 + (wc >> 1) * 8192 + ((wc & 1) * 64 + li) * 64;
  const u32 aA0 = (u32)(size_t)(las_ptr)&lds[aBase + u0];
  const u32 aA1 = (u32)(size_t)(las_ptr)&lds[aBase + u1];
  const u32 bA0 = (u32)(size_t)(las_ptr)&lds[bBase + u0];
  const u32 bA1 = (u32)(size_t)(las_ptr)&lds[bBase + u1];

  f32x4_t acc[8][4] = {};

  auto stA = [&](int b, int t, int h) {
    #pragma unroll
    for (int l = 0; l < 2; l++)
      __builtin_amdgcn_global_load_lds((gas_ptr)(pA[h*2+l] + t * 64),
          (las_ptr)&lds[b * 32768 + h * 8192 + l * 4096 + ldsw], 16, 0, 0);
  };
  auto stB = [&](int b, int t, int h) {
    #pragma unroll
    for (int l = 0; l < 2; l++)
      __builtin_amdgcn_global_load_lds((gas_ptr)(pB[h*2+l] + t * 64),
          (las_ptr)&lds[b * 32768 + 16384 + h * 8192 + l * 4096 + ldsw], 16, 0, 0);
  };

  bf16x8_t A03[8], A47[8], Bq[4], Bq2[4];

  // prologue: B(0), A(0) -> buf0; B(1) -> buf1; wait tile 0 landed
  stB(0, 0, 0); stB(0, 0, 1); stA(0, 0, 0); stA(0, 0, 1); stB(1, 1, 0); stB(1, 1, 1);
  VMCNT4();
  SBAR();

  #pragma unroll
  for (int j = 0; j < 4; j++) {
    #pragma unroll
    for (int half = 0; half < 2; half++) {
      const u32 bo = half * 65536;
      const u32 xA0 = aA0 + bo, xA1 = aA1 + bo, xB0 = bA0 + bo, xB1 = bA1 + bo;
      // ---- pA: read A03 + Bq ----
      RD(A03[0], xA0, "0");    RD(A03[1], xA1, "0");
      RD(A03[2], xA0, "2048"); RD(A03[3], xA1, "2048");
      RD(A03[4], xA0, "4096"); RD(A03[5], xA1, "4096");
      RD(A03[6], xA0, "6144"); RD(A03[7], xA1, "6144");
      RD(Bq[0],  xB0, "0");    RD(Bq[1],  xB1, "0");
      RD(Bq[2],  xB0, "2048"); RD(Bq[3],  xB1, "2048");
      if (half == 0) stA(1, 2*j + 1, 0); else if (j < 3) stA(0, 2*j + 2, 0);
      SBAR();
      WAIT_LGKM0();
      MFMA_Q(0, 0, A03, Bq);
      SBAR();
      // ---- pB: read Bq2 ----
      RD(Bq2[0], xB0, "4096"); RD(Bq2[1], xB1, "4096");
      RD(Bq2[2], xB0, "6144"); RD(Bq2[3], xB1, "6144");
      if (half == 0) stA(1, 2*j + 1, 1); else if (j < 3) stA(0, 2*j + 2, 1);
      SBAR();
      WAIT_LGKM0();
      MFMA_Q(0, 2, A03, Bq2);
      SBAR();
      // ---- pC: read A47 ----
      RD(A47[0], xA0, "8192");  RD(A47[1], xA1, "8192");
      RD(A47[2], xA0, "10240"); RD(A47[3], xA1, "10240");
      RD(A47[4], xA0, "12288"); RD(A47[5], xA1, "12288");
      RD(A47[6], xA0, "14336"); RD(A47[7], xA1, "14336");
      if (j < 3) { if (half == 0) stB(0, 2*j + 2, 0); else stB(1, 2*j + 3, 0); }
      SBAR();
      WAIT_LGKM0();
      MFMA_Q(4, 0, A47, Bq);
      SBAR();
      // ---- pD: K-tile boundary ----
      if (j < 3) { if (half == 0) stB(0, 2*j + 2, 1); else stB(1, 2*j + 3, 1); }
      if (half == 0) { if (j < 3) VMCNT4(); else VMCNT0(); }
      else           { if (j < 3) VMCNT4(); }
      SBAR();
      MFMA_Q(4, 2, A47, Bq2);
      SBAR();
    }
  }

  // epilogue: per-row argmax over this block's 256 cols (wave owns 64 cols)
  #pragma unroll
  for (int m = 0; m < 8; m++) {
    #pragma unroll
    for (int j = 0; j < 4; j++) {
      u64 best = 0;
      #pragma unroll
      for (int n = 0; n < 4; n++) {
        float v = acc[m][n][j];
        u32 col = (u32)(bcol + wc * 64 + n * 16 + li);
        u64 key = ((u64)fkey(v) << 32) | (u64)(0xFFFFFFFFu - col);
        best = best > key ? best : key;
      }
      #pragma unroll
      for (int off = 1; off < 16; off <<= 1) {
        u64 o = __shfl_xor(best, off);
        best = best > o ? best : o;
      }
      if (li == 0) {
        int row = brow + wr * 128 + m * 16 + lg * 4 + j;
        part[(size_t)row * 512 + (qt * 4 + wc)] = best;
      }
    }
  }
}

// ---------------- kernel 3: reduce argmax partials -> nn_idx ----------------
__global__ void k_argmax_reduce(const u64* __restrict__ part, int* __restrict__ nnidx) {
  int row = (int)((blockIdx.x * blockDim.x + threadIdx.x) >> 6);
  int lane = threadIdx.x & 63;
  const u64* p = part + (size_t)row * 512;
  u64 best = 0;
  #pragma unroll
  for (int i = 0; i < 8; i++) { u64 v = p[lane * 8 + i]; best = best > v ? best : v; }
  #pragma unroll
  for (int off = 1; off < 64; off <<= 1) { u64 o = __shfl_xor(best, off); best = best > o ? best : o; }
  if (lane == 0) nnidx[row] = (int)(0xFFFFFFFFu - (u32)(best & 0xFFFFFFFFu));
}

// ---------------- kernel 4: sim = nn_feats @ features^T / T, fused lse + positives ----
__global__ __launch_bounds__(512, 2) void k_sim_gemm(
    const u16* __restrict__ featb, const u16* __restrict__ queueb,
    const int* __restrict__ nnidx,
    float2* __restrict__ lsep, float* __restrict__ pos) {
  __shared__ u16 lds[65536];
  const int tid = threadIdx.x;
  const int w = tid >> 6, lane = tid & 63;
  const int wr = w >> 2, wc = w & 3;
  const int li = lane & 15, lg = lane >> 4;
  const int bid = (int)blockIdx.x;
  const int wg = (bid & 7) * 32 + (bid >> 3);     // XCD swizzle (256 = 8x32)
  const int mt = wg & 15, ct = wg >> 4;
  const int brow = mt * 256, bcol = ct * 256;

  const int srw = tid >> 3;
  const int ssl = (tid & 7) ^ ((tid >> 3) & 7);
  const int ldsw = w * 512;
  const u16* pA[4]; const u16* pB[4];
  #pragma unroll
  for (int h = 0; h < 2; h++)
    #pragma unroll
    for (int l = 0; l < 2; l++) {
      pA[h*2+l] = queueb + (size_t)nnidx[brow + h*128 + l*64 + srw] * DDIM + ssl * 8;
      pB[h*2+l] = featb  + (size_t)(bcol + h*128 + l*64 + srw) * DDIM + ssl * 8;
    }

  const int sx = li & 7;
  const int u0 = (lg ^ sx) * 8;
  const int u1 = ((4 + lg) ^ sx) * 8;
  const int aBase = wr * 8192 + li * 64;
  const int bBase = 16384 + (wc >> 1) * 8192 + ((wc & 1) * 64 + li) * 64;
  const u32 aA0 = (u32)(size_t)(las_ptr)&lds[aBase + u0];
  const u32 aA1 = (u32)(size_t)(las_ptr)&lds[aBase + u1];
  const u32 bA0 = (u32)(size_t)(las_ptr)&lds[bBase + u0];
  const u32 bA1 = (u32)(size_t)(las_ptr)&lds[bBase + u1];

  f32x4_t acc[8][4] = {};

  auto stA = [&](int b, int t, int h) {
    #pragma unroll
    for (int l = 0; l < 2; l++)
      __builtin_amdgcn_global_load_lds((gas_ptr)(pA[h*2+l] + t * 64),
          (las_ptr)&lds[b * 32768 + h * 8192 + l * 4096 + ldsw], 16, 0, 0);
  };
  auto stB = [&](int b, int t, int h) {
    #pragma unroll
    for (int l = 0; l < 2; l++)
      __builtin_amdgcn_global_load_lds((gas_ptr)(pB[h*2+l] + t * 64),
          (las_ptr)&lds[b * 32768 + 16384 + h * 8192 + l * 4096 + ldsw], 16, 0, 0);
  };

  bf16x8_t A03[8], A47[8], Bq[4], Bq2[4];

  stB(0, 0, 0); stB(0, 0, 1); stA(0, 0, 0); stA(0, 0, 1); stB(1, 1, 0); stB(1, 1, 1);
  VMCNT4();
  SBAR();

  #pragma unroll
  for (int j = 0; j < 4; j++) {
    #pragma unroll
    for (int half = 0; half < 2; half++) {
      const u32 bo = half * 65536;
      const u32 xA0 = aA0 + bo, xA1 = aA1 + bo, xB0 = bA0 + bo, xB1 = bA1 + bo;
      RD(A03[0], xA0, "0");    RD(A03[1], xA1, "0");
      RD(A03[2], xA0, "2048"); RD(A03[3], xA1, "2048");
      RD(A03[4], xA0, "4096"); RD(A03[5], xA1, "4096");
      RD(A03[6], xA0, "6144"); RD(A03[7], xA1, "6144");
      RD(Bq[0],  xB0, "0");    RD(Bq[1],  xB1, "0");
      RD(Bq[2],  xB0, "2048"); RD(Bq[3],  xB1, "2048");
      if (half == 0) stA(1, 2*j + 1, 0); else if (j < 3) stA(0, 2*j + 2, 0);
      SBAR();
      WAIT_LGKM0();
      MFMA_Q(0, 0, A03, Bq);
      SBAR();
      RD(Bq2[0], xB0, "4096"); RD(Bq2[1], xB1, "4096");
      RD(Bq2[2], xB0, "6144"); RD(Bq2[3], xB1, "6144");
      if (half == 0) stA(1, 2*j + 1, 1); else if (j < 3) stA(0, 2*j + 2, 1);
      SBAR();
      WAIT_LGKM0();
      MFMA_Q(0, 2, A03, Bq2);
      SBAR();
      RD(A47[0], xA0, "8192");  RD(A47[1], xA1, "8192");
      RD(A47[2], xA0, "10240"); RD(A47[3], xA1, "10240");
      RD(A47[4], xA0, "12288"); RD(A47[5], xA1, "12288");
      RD(A47[6], xA0, "14336"); RD(A47[7], xA1, "14336");
      if (j < 3) { if (half == 0) stB(0, 2*j + 2, 0); else stB(1, 2*j + 3, 0); }
      SBAR();
      WAIT_LGKM0();
      MFMA_Q(4, 0, A47, Bq);
      SBAR();
      if (j < 3) { if (half == 0) stB(0, 2*j + 2, 1); else stB(1, 2*j + 3, 1); }
      if (half == 0) { if (j < 3) VMCNT4(); else VMCNT0(); }
      else           { if (j < 3) VMCNT4(); }
      SBAR();
      MFMA_Q(4, 2, A47, Bq2);
      SBAR();
    }
  }

  // epilogue: scale by 1/T=2, positives, diag mask, per-row (max, sumexp) over 64 cols
  #pragma unroll
  for (int m = 0; m < 8; m++) {
    #pragma unroll
    for (int j = 0; j < 4; j++) {
      int row = brow + wr * 128 + m * 16 + lg * 4 + j;
      float vals[4];
      float vmax = -3.0e38f;
      #pragma unroll
      for (int n = 0; n < 4; n++) {
        int col = bcol + wc * 64 + n * 16 + li;
        float v = acc[m][n][j] * 2.0f;
        if (col == (row ^ NHALF)) pos[row] = v;   // positive sample (unique writer)
        if (col == row) v = -1.0e30f;             // diag mask
        vals[n] = v;
        vmax = fmaxf(vmax, v);
      }
      float sum = 0.f;
      #pragma unroll
      for (int n = 0; n < 4; n++) sum += __expf(vals[n] - vmax);
      #pragma unroll
      for (int off = 1; off < 16; off <<= 1) {
        float mo = __shfl_xor(vmax, off);
        float so = __shfl_xor(sum, off);
        float M = fmaxf(vmax, mo);
        sum = sum * __expf(vmax - M) + so * __expf(mo - M);
        vmax = M;
      }
      if (li == 0) lsep[(size_t)row * 64 + (ct * 4 + wc)] = make_float2(vmax, sum);
    }
  }
}

// ---------------- kernel 5: per-row logsumexp merge ----------------
__global__ void k_lse(const float2* __restrict__ lsep, float* __restrict__ lse) {
  int row = (int)((blockIdx.x * blockDim.x + threadIdx.x) >> 6);
  int lane = threadIdx.x & 63;
  float2 p = lsep[(size_t)row * 64 + lane];
  float m = p.x, s = p.y;
  #pragma unroll
  for (int off = 1; off < 64; off <<= 1) {
    float mo = __shfl_xor(m, off), so = __shfl_xor(s, off);
    float M = fmaxf(m, mo);
    s = s * __expf(m - M) + so * __expf(mo - M);
    m = M;
  }
  if (lane == 0) lse[row] = m + __logf(s);
}

// ---------------- kernel 6: final scalar ----------------
__global__ void k_final(const float* __restrict__ lse, const float* __restrict__ pos,
                        float* __restrict__ out) {
  __shared__ float red[4];
  int tid = threadIdx.x;
  float a = 0.f;
  for (int i = tid; i < NFEAT; i += 256) a += lse[i] - pos[i];
  #pragma unroll
  for (int off = 32; off >= 1; off >>= 1) a += __shfl_xor(a, off);
  if ((tid & 63) == 0) red[tid >> 6] = a;
  __syncthreads();
  if (tid == 0) out[0] = (red[0] + red[1] + red[2] + red[3]) / (float)NFEAT;
}

extern "C" void kernel_launch(void* const* d_in, const int* in_sizes, int n_in,
                              void* d_out, int out_size, void* d_ws, size_t ws_size,
                              hipStream_t stream) {
  const float* zi    = (const float*)d_in[0];
  const float* zj    = (const float*)d_in[1];
  const float* queue = (const float*)d_in[2];
  float* out = (float*)d_out;
  char* ws = (char*)d_ws;

  // ws layout (bytes):
  u16*    queueb = (u16*)(ws + 0);               // 32768*512*2 = 33554432
  u16*    featb  = (u16*)(ws + 33554432);        // 4096*512*2  = 4194304
  u64*    part   = (u64*)(ws + 37748736);        // 4096*512*8  = 16777216
  int*    nnidx  = (int*)(ws + 54525952);        // 4096*4      = 16384
  float2* lsep   = (float2*)(ws + 54542336);     // 4096*64*8   = 2097152
  float*  pos    = (float*)(ws + 56639488);      // 4096*4      = 16384
  float*  lse    = (float*)(ws + 56655872);      // 4096*4      = 16384
  // total = 56672256 bytes (~54 MB)

  k_norm<<<9216, 256, 0, stream>>>(zi, zj, queue, featb, queueb);
  k_argmax_gemm<<<2048, 512, 0, stream>>>(featb, queueb, part);
  k_argmax_reduce<<<1024, 256, 0, stream>>>(part, nnidx);
  k_sim_gemm<<<256, 512, 0, stream>>>(featb, queueb, nnidx, lsep, pos);
  k_lse<<<1024, 256, 0, stream>>>(lsep, lse);
  k_final<<<1, 256, 0, stream>>>(lse, pos, out);
}